// Round 15
// baseline (335.579 us; speedup 1.0000x reference)
//
#include <hip/hip_runtime.h>
#include <hip/hip_bf16.h>
#include <stdint.h>

#define NTOK 4096
#define DM 1024
#define FF 2048
#define F2 4096
#define NEXP 8
#define PAIR_CAP 10240

typedef __bf16 bf16x8 __attribute__((ext_vector_type(8)));
typedef float f32x4 __attribute__((ext_vector_type(4)));

__device__ __forceinline__ unsigned short bf16_rne(float f) {
    union { float f; unsigned int u; } v; v.f = f;
    unsigned int u = v.u;
    return (unsigned short)((u + 0x7FFFu + ((u >> 16) & 1u)) >> 16);
}

__device__ __forceinline__ f32x4 MFMA16(bf16x8 a, bf16x8 b, f32x4 c) {
    return __builtin_amdgcn_mfma_f32_16x16x32_bf16(a, b, c, 0, 0, 0);
}

__device__ __forceinline__ void gload16(const void* g, void* l) {
    __builtin_amdgcn_global_load_lds(
        (const __attribute__((address_space(1))) uint32_t*)g,
        (__attribute__((address_space(3))) uint32_t*)l, 16, 0, 0);
}

// ---------------- gating: scores (fp32), top-2 softmax, x -> bf16; NO atomics ----------------
__global__ __launch_bounds__(256) void k_gate(const float* __restrict__ x,
                                              const float* __restrict__ Wg,
                                              unsigned short* __restrict__ xbf,
                                              int* __restrict__ te, float* __restrict__ tw) {
    int t = blockIdx.x * 4 + (threadIdx.x >> 6);
    int l = threadIdx.x & 63;
    const float* xr = x + (size_t)t * DM + l * 16;
    float xv[16];
#pragma unroll
    for (int i = 0; i < 4; ++i) {
        float4 v = ((const float4*)xr)[i];
        xv[4*i+0] = v.x; xv[4*i+1] = v.y; xv[4*i+2] = v.z; xv[4*i+3] = v.w;
    }
    unsigned int pk[8];
#pragma unroll
    for (int i = 0; i < 8; ++i)
        pk[i] = (unsigned int)bf16_rne(xv[2*i]) | ((unsigned int)bf16_rne(xv[2*i+1]) << 16);
    uint4* dst = (uint4*)(xbf + (size_t)t * DM + l * 16);
    dst[0] = make_uint4(pk[0], pk[1], pk[2], pk[3]);
    dst[1] = make_uint4(pk[4], pk[5], pk[6], pk[7]);

    float s[NEXP];
#pragma unroll
    for (int e = 0; e < NEXP; ++e) {
        const float* wr = Wg + e * DM + l * 16;
        float acc = 0.f;
#pragma unroll
        for (int i = 0; i < 4; ++i) {
            float4 v = ((const float4*)wr)[i];
            acc += v.x * xv[4*i] + v.y * xv[4*i+1] + v.z * xv[4*i+2] + v.w * xv[4*i+3];
        }
        s[e] = acc;
    }
#pragma unroll
    for (int off = 32; off > 0; off >>= 1) {
#pragma unroll
        for (int e = 0; e < NEXP; ++e) s[e] += __shfl_xor(s[e], off, 64);
    }
    if (l == 0) {
        int e0 = 0; float v0 = s[0];
        for (int e = 1; e < NEXP; ++e) if (s[e] > v0) { v0 = s[e]; e0 = e; }
        int e1 = -1; float v1 = -1e30f;
        for (int e = 0; e < NEXP; ++e) if (e != e0 && s[e] > v1) { v1 = s[e]; e1 = e; }
        float w0 = 1.f / (1.f + __expf(v1 - v0));
        float w1 = 1.f - w0;
        te[2*t] = e0; te[2*t+1] = e1;
        tw[2*t] = w0; tw[2*t+1] = w1;
    }
}

// ---------------- route: deterministic prefix-sum placement, NO atomics, 1 block ----------------
__global__ __launch_bounds__(256) void k_route(const int* __restrict__ te,
                                               const float* __restrict__ tw,
                                               int* __restrict__ pair_tok, float* __restrict__ pair_w,
                                               int* __restrict__ slot_of,
                                               int* __restrict__ cnt_pad, int* __restrict__ off_pad) {
    __shared__ int lc[256][NEXP];
    __shared__ int opad[NEXP];
    int t = threadIdx.x;
    for (int i = t; i < PAIR_CAP; i += 256) { pair_tok[i] = 0; pair_w[i] = 0.f; }
    int ev[32];
    int c[NEXP];
#pragma unroll
    for (int e = 0; e < NEXP; ++e) c[e] = 0;
#pragma unroll
    for (int j = 0; j < 32; ++j) {
        ev[j] = te[t * 32 + j];
#pragma unroll
        for (int e = 0; e < NEXP; ++e) c[e] += (ev[j] == e) ? 1 : 0;
    }
#pragma unroll
    for (int e = 0; e < NEXP; ++e) lc[t][e] = c[e];
    __syncthreads();
    if (t < NEXP) {
        int run = 0;
        for (int i = 0; i < 256; ++i) { int v = lc[i][t]; lc[i][t] = run; run += v; }
        opad[t] = run;
    }
    __syncthreads();
    if (t == 0) {
        int o = 0;
        for (int e = 0; e < NEXP; ++e) {
            int tot = opad[e];
            int cp = ((tot + 127) >> 7) << 7;
            cnt_pad[e] = cp; off_pad[e] = o; opad[e] = o; o += cp;
        }
    }
    __syncthreads();
    int cur[NEXP];
#pragma unroll
    for (int e = 0; e < NEXP; ++e) cur[e] = opad[e] + lc[t][e];
#pragma unroll
    for (int j = 0; j < 32; ++j) {
        int p = t * 32 + j;
        int slot = 0;
#pragma unroll
        for (int e = 0; e < NEXP; ++e) {
            bool m = (ev[j] == e);
            if (m) slot = cur[e];
            cur[e] += m ? 1 : 0;
        }
        pair_tok[slot] = p >> 1;
        pair_w[slot] = tw[p];
        slot_of[p] = slot;
    }
}

// ---------------- cvt1: W1 fp32 [e][1024k][4096f] -> W1T bf16 [e][4096n][1024k] ----------------
__global__ __launch_bounds__(256) void k_cvt1(const float* __restrict__ W1,
                                              unsigned short* __restrict__ WT) {
    __shared__ float lt[64][65];
    int e = blockIdx.z, nt = blockIdx.y, kt = blockIdx.x;
    int col0 = (nt < 32) ? (nt * 64) : (FF + (nt - 32) * 64);
    const float* src = W1 + (size_t)e * DM * F2 + (size_t)(kt * 64) * F2 + col0;
    int t = threadIdx.x;
#pragma unroll
    for (int i = 0; i < 4; ++i) {
        int flat = i * 256 + t;
        int k = flat >> 4, c4 = (flat & 15) * 4;
        float4 v = *(const float4*)(src + (size_t)k * F2 + c4);
        lt[k][c4] = v.x; lt[k][c4+1] = v.y; lt[k][c4+2] = v.z; lt[k][c4+3] = v.w;
    }
    __syncthreads();
    unsigned short* dst = WT + ((size_t)e * 4096 + nt * 64) * 1024 + kt * 64;
#pragma unroll
    for (int i = 0; i < 4; ++i) {
        int flat = i * 256 + t;
        int n = flat >> 4, kc = (flat & 15) * 4;
        unsigned int lo = (unsigned int)bf16_rne(lt[kc][n])   | ((unsigned int)bf16_rne(lt[kc+1][n]) << 16);
        unsigned int hi = (unsigned int)bf16_rne(lt[kc+2][n]) | ((unsigned int)bf16_rne(lt[kc+3][n]) << 16);
        *(uint2*)(dst + (size_t)n * 1024 + kc) = make_uint2(lo, hi);
    }
}

// ---------------- cvt2: W2 fp32 -> W2T bf16 [e][1024n][2048k] ----------------
__global__ __launch_bounds__(256) void k_cvt2(const float* __restrict__ W2,
                                              unsigned short* __restrict__ WT) {
    __shared__ float lt[64][65];
    int e = blockIdx.z, nt = blockIdx.y, kt = blockIdx.x;
    const float* src = W2 + (size_t)e * FF * DM + (size_t)(kt * 64) * DM + nt * 64;
    int t = threadIdx.x;
#pragma unroll
    for (int i = 0; i < 4; ++i) {
        int flat = i * 256 + t;
        int k = flat >> 4, c4 = (flat & 15) * 4;
        float4 v = *(const float4*)(src + (size_t)k * DM + c4);
        lt[k][c4] = v.x; lt[k][c4+1] = v.y; lt[k][c4+2] = v.z; lt[k][c4+3] = v.w;
    }
    __syncthreads();
    unsigned short* dst = WT + ((size_t)e * 1024 + nt * 64) * 2048 + kt * 64;
#pragma unroll
    for (int i = 0; i < 4; ++i) {
        int flat = i * 256 + t;
        int n = flat >> 4, kc = (flat & 15) * 4;
        unsigned int lo = (unsigned int)bf16_rne(lt[kc][n])   | ((unsigned int)bf16_rne(lt[kc+1][n]) << 16);
        unsigned int hi = (unsigned int)bf16_rne(lt[kc+2][n]) | ((unsigned int)bf16_rne(lt[kc+3][n]) << 16);
        *(uint2*)(dst + (size_t)n * 2048 + kc) = make_uint2(lo, hi);
    }
}

// ---------------- GEMM1: 128 rows x 64 hh-cols, 4 waves, 32KB, declared 5 blocks/CU ----------------
// grid 8192 XCD-chunked; lid = c0t(5b) | yt(5b) | e(3b); active ~2048
__global__ __launch_bounds__(256, 5) void k_gemm1(const unsigned short* __restrict__ xbf,
                                                  const unsigned short* __restrict__ W1T,
                                                  const float* __restrict__ b1,
                                                  const int* __restrict__ pair_tok,
                                                  const int* __restrict__ cnt_pad,
                                                  const int* __restrict__ off_pad,
                                                  unsigned short* __restrict__ hh) {
    int id = blockIdx.x;
    int lid = (id & 7) * 1024 + (id >> 3);
    int c0t = lid & 31, yt = (lid >> 5) & 31, e = lid >> 10;
    if (yt * 128 >= cnt_pad[e]) return;
    int row0 = off_pad[e] + yt * 128;
    int c0 = c0t * 64;
    const unsigned short* WTe = W1T + (size_t)e * 4096 * 1024;

    __shared__ unsigned short lA[128 * 64];
    __shared__ unsigned short lB[128 * 64];

    int t = threadIdx.x, w = t >> 6, l = t & 63;
    int wm = w >> 1, wn = w & 1;

    const unsigned short* asrc[4];
    const unsigned short* bsrc[4];
    unsigned short* adst[4];
    unsigned short* bdst[4];
    int c8 = ((l & 7) ^ (l >> 3)) * 8;
#pragma unroll
    for (int q = 0; q < 4; ++q) {
        int r = w * 32 + q * 8 + (l >> 3);
        int tok = pair_tok[row0 + r];
        asrc[q] = xbf + (size_t)tok * DM + c8;
        adst[q] = lA + (w * 32 + q * 8) * 64;
        int bn = (r < 64) ? (c0 + r) : (2048 + c0 + (r - 64));   // a rows then g rows
        bsrc[q] = WTe + (size_t)bn * 1024 + c8;
        bdst[q] = lB + (w * 32 + q * 8) * 64;
    }

    f32x4 aca[4][2], acg[4][2];
#pragma unroll
    for (int m = 0; m < 4; ++m)
#pragma unroll
        for (int fn = 0; fn < 2; ++fn) { aca[m][fn] = (f32x4){0,0,0,0}; acg[m][fn] = (f32x4){0,0,0,0}; }

#pragma unroll
    for (int q = 0; q < 4; ++q) { gload16(asrc[q], adst[q]); gload16(bsrc[q], bdst[q]); }

    int lr = l & 15, kg = l >> 4;
    for (int kt = 0; kt < 16; ++kt) {
        __syncthreads();
#pragma unroll
        for (int ks = 0; ks < 2; ++ks) {
            int kc = ks * 64 + kg * 16;
            bf16x8 af[4];
#pragma unroll
            for (int m = 0; m < 4; ++m) {
                int row = wm * 64 + m * 16 + lr;
                af[m] = *(const bf16x8*)((const char*)lA + row * 128 + (kc ^ ((row & 7) << 4)));
            }
#pragma unroll
            for (int fn = 0; fn < 2; ++fn) {
                int na = wn * 32 + fn * 16 + lr;
                bf16x8 ba = *(const bf16x8*)((const char*)lB + na * 128 + (kc ^ ((na & 7) << 4)));
                bf16x8 bg = *(const bf16x8*)((const char*)lB + (na + 64) * 128 + (kc ^ ((na & 7) << 4)));
#pragma unroll
                for (int m = 0; m < 4; ++m) {
                    aca[m][fn] = MFMA16(af[m], ba, aca[m][fn]);
                    acg[m][fn] = MFMA16(af[m], bg, acg[m][fn]);
                }
            }
        }
        __syncthreads();
        if (kt < 15) {
#pragma unroll
            for (int q = 0; q < 4; ++q) {
                gload16(asrc[q] + (kt + 1) * 64, adst[q]);
                gload16(bsrc[q] + (kt + 1) * 64, bdst[q]);
            }
        }
    }
#pragma unroll
    for (int m = 0; m < 4; ++m)
#pragma unroll
        for (int fn = 0; fn < 2; ++fn) {
            int colh = c0 + wn * 32 + fn * 16 + lr;   // hh col 0..2047
            float ba1 = b1[e * F2 + colh], bg1 = b1[e * F2 + FF + colh];
#pragma unroll
            for (int j = 0; j < 4; ++j) {
                int row = wm * 64 + m * 16 + kg * 4 + j;
                float a = aca[m][fn][j] + ba1;
                float g = acg[m][fn][j] + bg1;
                float sg = a / (1.f + __expf(-a)) * g;
                hh[(size_t)(row0 + row) * FF + colh] = bf16_rne(sg);
            }
        }
}

// ---------------- GEMM2: 128 rows x 64 d-cols, 4 waves, 24KB, declared 6 blocks/CU ----------------
__global__ __launch_bounds__(256, 6) void k_gemm2(const unsigned short* __restrict__ hh,
                                                  const unsigned short* __restrict__ W2T,
                                                  const float* __restrict__ b2,
                                                  const int* __restrict__ pair_tok,
                                                  const float* __restrict__ pair_w,
                                                  const int* __restrict__ cnt_pad,
                                                  const int* __restrict__ off_pad,
                                                  float* __restrict__ eo_or_out, int mode) {
    int id = blockIdx.x;
    int lid = (id & 7) * 512 + (id >> 3);
    int d0t = lid & 15, yt = (lid >> 4) & 31, e = lid >> 9;
    if (yt * 128 >= cnt_pad[e]) return;
    int row0 = off_pad[e] + yt * 128;
    int d0 = d0t * 64;
    const unsigned short* WTe = W2T + (size_t)e * 1024 * 2048;

    __shared__ unsigned short lA[128 * 64];
    __shared__ unsigned short lB[64 * 64];

    int t = threadIdx.x, w = t >> 6, l = t & 63;
    int wm = w >> 1, wn = w & 1;

    const unsigned short* asrc[4];
    const unsigned short* bsrc[2];
    unsigned short* adst[4];
    unsigned short* bdst[2];
    int c8 = ((l & 7) ^ (l >> 3)) * 8;
#pragma unroll
    for (int q = 0; q < 4; ++q) {
        int r = w * 32 + q * 8 + (l >> 3);
        asrc[q] = hh + (size_t)(row0 + r) * FF + c8;
        adst[q] = lA + (w * 32 + q * 8) * 64;
    }
#pragma unroll
    for (int q = 0; q < 2; ++q) {
        int r = w * 16 + q * 8 + (l >> 3);
        bsrc[q] = WTe + (size_t)(d0 + r) * 2048 + c8;
        bdst[q] = lB + (w * 16 + q * 8) * 64;
    }

    f32x4 ac[4][2];
#pragma unroll
    for (int m = 0; m < 4; ++m)
#pragma unroll
        for (int fn = 0; fn < 2; ++fn) ac[m][fn] = (f32x4){0,0,0,0};

#pragma unroll
    for (int q = 0; q < 4; ++q) gload16(asrc[q], adst[q]);
#pragma unroll
    for (int q = 0; q < 2; ++q) gload16(bsrc[q], bdst[q]);

    int lr = l & 15, kg = l >> 4;
    for (int kt = 0; kt < 32; ++kt) {
        __syncthreads();
#pragma unroll
        for (int ks = 0; ks < 2; ++ks) {
            int kc = ks * 64 + kg * 16;
            bf16x8 af[4];
#pragma unroll
            for (int m = 0; m < 4; ++m) {
                int row = wm * 64 + m * 16 + lr;
                af[m] = *(const bf16x8*)((const char*)lA + row * 128 + (kc ^ ((row & 7) << 4)));
            }
#pragma unroll
            for (int fn = 0; fn < 2; ++fn) {
                int n = wn * 32 + fn * 16 + lr;
                bf16x8 bb = *(const bf16x8*)((const char*)lB + n * 128 + (kc ^ ((n & 7) << 4)));
#pragma unroll
                for (int m = 0; m < 4; ++m) ac[m][fn] = MFMA16(af[m], bb, ac[m][fn]);
            }
        }
        __syncthreads();
        if (kt < 31) {
#pragma unroll
            for (int q = 0; q < 4; ++q) gload16(asrc[q] + (kt + 1) * 64, adst[q]);
#pragma unroll
            for (int q = 0; q < 2; ++q) gload16(bsrc[q] + (kt + 1) * 64, bdst[q]);
        }
    }

    if (mode == 0) {
#pragma unroll
        for (int m = 0; m < 4; ++m)
#pragma unroll
            for (int fn = 0; fn < 2; ++fn) {
                int col = d0 + wn * 32 + fn * 16 + lr;
#pragma unroll
                for (int j = 0; j < 4; ++j) {
                    int row = wm * 64 + m * 16 + kg * 4 + j;
                    int pr = row0 + row;
                    eo_or_out[(size_t)pr * DM + col] = pair_w[pr] * ac[m][fn][j];
                }
            }
    } else {
#pragma unroll
        for (int m = 0; m < 4; ++m)
#pragma unroll
            for (int fn = 0; fn < 2; ++fn) {
                int col = d0 + wn * 32 + fn * 16 + lr;
                float b2v = b2[e * DM + col];
#pragma unroll
                for (int j = 0; j < 4; ++j) {
                    int row = wm * 64 + m * 16 + kg * 4 + j;
                    int pr = row0 + row;
                    atomicAdd(eo_or_out + (size_t)pair_tok[pr] * DM + col,
                              pair_w[pr] * (ac[m][fn][j] + b2v));
                }
            }
    }
}

// ---------------- combine: out[t] = eo[s0]+eo[s1] + w0*b2[e0] + w1*b2[e1] ----------------
__global__ __launch_bounds__(256) void k_comb(const float* __restrict__ eo,
                                              const int* __restrict__ slot_of,
                                              const int* __restrict__ te,
                                              const float* __restrict__ tw,
                                              const float* __restrict__ b2,
                                              float* __restrict__ out) {
    int t = blockIdx.x;
    int d = threadIdx.x * 4;
    int s0 = slot_of[2*t], s1 = slot_of[2*t+1];
    int e0 = te[2*t], e1 = te[2*t+1];
    float w0 = tw[2*t], w1 = tw[2*t+1];
    float4 a = *(const float4*)(eo + (size_t)s0 * DM + d);
    float4 b = *(const float4*)(eo + (size_t)s1 * DM + d);
    float4 p = *(const float4*)(b2 + (size_t)e0 * DM + d);
    float4 q = *(const float4*)(b2 + (size_t)e1 * DM + d);
    float4 r;
    r.x = a.x + b.x + w0 * p.x + w1 * q.x;
    r.y = a.y + b.y + w0 * p.y + w1 * q.y;
    r.z = a.z + b.z + w0 * p.z + w1 * q.z;
    r.w = a.w + b.w + w0 * p.w + w1 * q.w;
    *(float4*)(out + (size_t)t * DM + d) = r;
}

// ---------------- host ----------------
extern "C" void kernel_launch(void* const* d_in, const int* in_sizes, int n_in,
                              void* d_out, int out_size, void* d_ws, size_t ws_size,
                              hipStream_t stream) {
    const float* x  = (const float*)d_in[0];
    const float* Wg = (const float*)d_in[1];
    const float* W1 = (const float*)d_in[2];
    const float* b1 = (const float*)d_in[3];
    const float* W2 = (const float*)d_in[4];
    const float* b2 = (const float*)d_in[5];
    float* out = (float*)d_out;

    char* ws = (char*)d_ws;
    unsigned short* xbf = (unsigned short*)ws;                        // 8.39 MB
    unsigned short* hh  = (unsigned short*)(ws + 8388608);            // 41.94 MB
    unsigned short* W1T = (unsigned short*)(ws + 50331648);           // 67.11 MB (full, both halves)
    unsigned short* W2Tm0 = (unsigned short*)(ws + 117440512);        // 33.55 MB
    float* eo           = (float*)(ws + 150994944);                   // 41.94 MB
    const size_t MODE0_END = 150994944ull + 41943040ull;              // 192.9 MB
    int mode = (ws_size >= MODE0_END + 262144) ? 0 : 1;
    size_t mb = (mode == 0) ? MODE0_END : 117440512ull;
    unsigned short* W2T = (mode == 0) ? W2Tm0 : (unsigned short*)(ws + 50331648);
    int*   pair_tok = (int*)(ws + mb);
    float* pair_w   = (float*)(ws + mb + 40960);
    int*   slot_of  = (int*)(ws + mb + 81920);
    int*   te       = (int*)(ws + mb + 114688);
    float* tw       = (float*)(ws + mb + 147456);
    int*   cnt_pad  = (int*)(ws + mb + 180224);
    int*   off_pad  = (int*)(ws + mb + 180352);

    if (mode == 1)
        hipMemsetAsync(d_out, 0, (size_t)out_size * sizeof(float), stream);

    k_gate<<<NTOK / 4, 256, 0, stream>>>(x, Wg, xbf, te, tw);
    k_route<<<1, 256, 0, stream>>>(te, tw, pair_tok, pair_w, slot_of, cnt_pad, off_pad);

    k_cvt1<<<dim3(16, 64, 8), 256, 0, stream>>>(W1, W1T);
    k_gemm1<<<8192, 256, 0, stream>>>(xbf, W1T, b1, pair_tok, cnt_pad, off_pad, hh);
    k_cvt2<<<dim3(32, 16, 8), 256, 0, stream>>>(W2, W2T);
    k_gemm2<<<4096, 256, 0, stream>>>(hh, W2T, b2, pair_tok, pair_w, cnt_pad, off_pad,
                                      (mode == 0) ? eo : out, mode);
    if (mode == 0)
        k_comb<<<NTOK, 256, 0, stream>>>(eo, slot_of, te, tw, b2, out);
}

// Round 16
// 226.620 us; speedup vs baseline: 1.4808x; 1.4808x over previous
//
#include <hip/hip_runtime.h>
#include <hip/hip_bf16.h>
#include <stdint.h>

#define NTOK 4096
#define DM 1024
#define FF 2048
#define F2 4096
#define NEXP 8
#define PAIR_CAP 10240

typedef __bf16 bf16x8 __attribute__((ext_vector_type(8)));
typedef float f32x4 __attribute__((ext_vector_type(4)));

__device__ __forceinline__ unsigned short bf16_rne(float f) {
    union { float f; unsigned int u; } v; v.f = f;
    unsigned int u = v.u;
    return (unsigned short)((u + 0x7FFFu + ((u >> 16) & 1u)) >> 16);
}

__device__ __forceinline__ f32x4 MFMA16(bf16x8 a, bf16x8 b, f32x4 c) {
    return __builtin_amdgcn_mfma_f32_16x16x32_bf16(a, b, c, 0, 0, 0);
}

__device__ __forceinline__ void gload16(const void* g, void* l) {
    __builtin_amdgcn_global_load_lds(
        (const __attribute__((address_space(1))) uint32_t*)g,
        (__attribute__((address_space(3))) uint32_t*)l, 16, 0, 0);
}

// ---------------- gating: scores (fp32), top-2 softmax, x -> bf16; NO atomics ----------------
__global__ __launch_bounds__(256) void k_gate(const float* __restrict__ x,
                                              const float* __restrict__ Wg,
                                              unsigned short* __restrict__ xbf,
                                              int* __restrict__ te, float* __restrict__ tw) {
    int t = blockIdx.x * 4 + (threadIdx.x >> 6);
    int l = threadIdx.x & 63;
    const float* xr = x + (size_t)t * DM + l * 16;
    float xv[16];
#pragma unroll
    for (int i = 0; i < 4; ++i) {
        float4 v = ((const float4*)xr)[i];
        xv[4*i+0] = v.x; xv[4*i+1] = v.y; xv[4*i+2] = v.z; xv[4*i+3] = v.w;
    }
    unsigned int pk[8];
#pragma unroll
    for (int i = 0; i < 8; ++i)
        pk[i] = (unsigned int)bf16_rne(xv[2*i]) | ((unsigned int)bf16_rne(xv[2*i+1]) << 16);
    uint4* dst = (uint4*)(xbf + (size_t)t * DM + l * 16);
    dst[0] = make_uint4(pk[0], pk[1], pk[2], pk[3]);
    dst[1] = make_uint4(pk[4], pk[5], pk[6], pk[7]);

    float s[NEXP];
#pragma unroll
    for (int e = 0; e < NEXP; ++e) {
        const float* wr = Wg + e * DM + l * 16;
        float acc = 0.f;
#pragma unroll
        for (int i = 0; i < 4; ++i) {
            float4 v = ((const float4*)wr)[i];
            acc += v.x * xv[4*i] + v.y * xv[4*i+1] + v.z * xv[4*i+2] + v.w * xv[4*i+3];
        }
        s[e] = acc;
    }
#pragma unroll
    for (int off = 32; off > 0; off >>= 1) {
#pragma unroll
        for (int e = 0; e < NEXP; ++e) s[e] += __shfl_xor(s[e], off, 64);
    }
    if (l == 0) {
        int e0 = 0; float v0 = s[0];
        for (int e = 1; e < NEXP; ++e) if (s[e] > v0) { v0 = s[e]; e0 = e; }
        int e1 = -1; float v1 = -1e30f;
        for (int e = 0; e < NEXP; ++e) if (e != e0 && s[e] > v1) { v1 = s[e]; e1 = e; }
        float w0 = 1.f / (1.f + __expf(v1 - v0));
        float w1 = 1.f - w0;
        te[2*t] = e0; te[2*t+1] = e1;
        tw[2*t] = w0; tw[2*t+1] = w1;
    }
}

// ---------------- route: deterministic prefix-sum placement, NO atomics, 1 block ----------------
__global__ __launch_bounds__(256) void k_route(const int* __restrict__ te,
                                               const float* __restrict__ tw,
                                               int* __restrict__ pair_tok, float* __restrict__ pair_w,
                                               int* __restrict__ slot_of,
                                               int* __restrict__ cnt_pad, int* __restrict__ off_pad) {
    __shared__ int lc[256][NEXP];
    __shared__ int opad[NEXP];
    int t = threadIdx.x;
    for (int i = t; i < PAIR_CAP; i += 256) { pair_tok[i] = 0; pair_w[i] = 0.f; }
    int ev[32];
    int c[NEXP];
#pragma unroll
    for (int e = 0; e < NEXP; ++e) c[e] = 0;
#pragma unroll
    for (int j = 0; j < 32; ++j) {
        ev[j] = te[t * 32 + j];
#pragma unroll
        for (int e = 0; e < NEXP; ++e) c[e] += (ev[j] == e) ? 1 : 0;
    }
#pragma unroll
    for (int e = 0; e < NEXP; ++e) lc[t][e] = c[e];
    __syncthreads();
    if (t < NEXP) {
        int run = 0;
        for (int i = 0; i < 256; ++i) { int v = lc[i][t]; lc[i][t] = run; run += v; }
        opad[t] = run;
    }
    __syncthreads();
    if (t == 0) {
        int o = 0;
        for (int e = 0; e < NEXP; ++e) {
            int tot = opad[e];
            int cp = ((tot + 127) >> 7) << 7;
            cnt_pad[e] = cp; off_pad[e] = o; opad[e] = o; o += cp;
        }
    }
    __syncthreads();
    int cur[NEXP];
#pragma unroll
    for (int e = 0; e < NEXP; ++e) cur[e] = opad[e] + lc[t][e];
#pragma unroll
    for (int j = 0; j < 32; ++j) {
        int p = t * 32 + j;
        int slot = 0;
#pragma unroll
        for (int e = 0; e < NEXP; ++e) {
            bool m = (ev[j] == e);
            if (m) slot = cur[e];
            cur[e] += m ? 1 : 0;
        }
        pair_tok[slot] = p >> 1;
        pair_w[slot] = tw[p];
        slot_of[p] = slot;
    }
}

// ---------------- cvt1: W1 fp32 [e][1024k][4096f] -> W1T bf16 [e][4096n][1024k] ----------------
__global__ __launch_bounds__(256) void k_cvt1(const float* __restrict__ W1,
                                              unsigned short* __restrict__ WT) {
    __shared__ float lt[64][65];
    int e = blockIdx.z, nt = blockIdx.y, kt = blockIdx.x;
    int col0 = (nt < 32) ? (nt * 64) : (FF + (nt - 32) * 64);
    const float* src = W1 + (size_t)e * DM * F2 + (size_t)(kt * 64) * F2 + col0;
    int t = threadIdx.x;
#pragma unroll
    for (int i = 0; i < 4; ++i) {
        int flat = i * 256 + t;
        int k = flat >> 4, c4 = (flat & 15) * 4;
        float4 v = *(const float4*)(src + (size_t)k * F2 + c4);
        lt[k][c4] = v.x; lt[k][c4+1] = v.y; lt[k][c4+2] = v.z; lt[k][c4+3] = v.w;
    }
    __syncthreads();
    unsigned short* dst = WT + ((size_t)e * 4096 + nt * 64) * 1024 + kt * 64;
#pragma unroll
    for (int i = 0; i < 4; ++i) {
        int flat = i * 256 + t;
        int n = flat >> 4, kc = (flat & 15) * 4;
        unsigned int lo = (unsigned int)bf16_rne(lt[kc][n])   | ((unsigned int)bf16_rne(lt[kc+1][n]) << 16);
        unsigned int hi = (unsigned int)bf16_rne(lt[kc+2][n]) | ((unsigned int)bf16_rne(lt[kc+3][n]) << 16);
        *(uint2*)(dst + (size_t)n * 1024 + kc) = make_uint2(lo, hi);
    }
}

// ---------------- cvt2: W2 fp32 -> W2T bf16 [e][1024n][2048k] ----------------
__global__ __launch_bounds__(256) void k_cvt2(const float* __restrict__ W2,
                                              unsigned short* __restrict__ WT) {
    __shared__ float lt[64][65];
    int e = blockIdx.z, nt = blockIdx.y, kt = blockIdx.x;
    const float* src = W2 + (size_t)e * FF * DM + (size_t)(kt * 64) * DM + nt * 64;
    int t = threadIdx.x;
#pragma unroll
    for (int i = 0; i < 4; ++i) {
        int flat = i * 256 + t;
        int k = flat >> 4, c4 = (flat & 15) * 4;
        float4 v = *(const float4*)(src + (size_t)k * DM + c4);
        lt[k][c4] = v.x; lt[k][c4+1] = v.y; lt[k][c4+2] = v.z; lt[k][c4+3] = v.w;
    }
    __syncthreads();
    unsigned short* dst = WT + ((size_t)e * 1024 + nt * 64) * 2048 + kt * 64;
#pragma unroll
    for (int i = 0; i < 4; ++i) {
        int flat = i * 256 + t;
        int n = flat >> 4, kc = (flat & 15) * 4;
        unsigned int lo = (unsigned int)bf16_rne(lt[kc][n])   | ((unsigned int)bf16_rne(lt[kc+1][n]) << 16);
        unsigned int hi = (unsigned int)bf16_rne(lt[kc+2][n]) | ((unsigned int)bf16_rne(lt[kc+3][n]) << 16);
        *(uint2*)(dst + (size_t)n * 2048 + kc) = make_uint2(lo, hi);
    }
}

// ---------------- GEMM1: 128 rows x 64 hh-cols, 4 waves, 32KB, 4/CU (R13 proven) ----------------
// grid 8192 XCD-chunked; lid = c0t(5b) | yt(5b) | e(3b); active ~2048
__global__ __launch_bounds__(256, 4) void k_gemm1(const unsigned short* __restrict__ xbf,
                                                  const unsigned short* __restrict__ W1T,
                                                  const float* __restrict__ b1,
                                                  const int* __restrict__ pair_tok,
                                                  const int* __restrict__ cnt_pad,
                                                  const int* __restrict__ off_pad,
                                                  unsigned short* __restrict__ hh) {
    int id = blockIdx.x;
    int lid = (id & 7) * 1024 + (id >> 3);
    int c0t = lid & 31, yt = (lid >> 5) & 31, e = lid >> 10;
    if (yt * 128 >= cnt_pad[e]) return;
    int row0 = off_pad[e] + yt * 128;
    int c0 = c0t * 64;
    const unsigned short* WTe = W1T + (size_t)e * 4096 * 1024;

    __shared__ unsigned short lA[128 * 64];
    __shared__ unsigned short lB[128 * 64];

    int t = threadIdx.x, w = t >> 6, l = t & 63;
    int wm = w >> 1, wn = w & 1;

    const unsigned short* asrc[4];
    const unsigned short* bsrc[4];
    unsigned short* adst[4];
    unsigned short* bdst[4];
    int c8 = ((l & 7) ^ (l >> 3)) * 8;
#pragma unroll
    for (int q = 0; q < 4; ++q) {
        int r = w * 32 + q * 8 + (l >> 3);
        int tok = pair_tok[row0 + r];
        asrc[q] = xbf + (size_t)tok * DM + c8;
        adst[q] = lA + (w * 32 + q * 8) * 64;
        int bn = (r < 64) ? (c0 + r) : (2048 + c0 + (r - 64));   // a rows then g rows
        bsrc[q] = WTe + (size_t)bn * 1024 + c8;
        bdst[q] = lB + (w * 32 + q * 8) * 64;
    }

    f32x4 aca[4][2], acg[4][2];
#pragma unroll
    for (int m = 0; m < 4; ++m)
#pragma unroll
        for (int fn = 0; fn < 2; ++fn) { aca[m][fn] = (f32x4){0,0,0,0}; acg[m][fn] = (f32x4){0,0,0,0}; }

#pragma unroll
    for (int q = 0; q < 4; ++q) { gload16(asrc[q], adst[q]); gload16(bsrc[q], bdst[q]); }

    int lr = l & 15, kg = l >> 4;
    for (int kt = 0; kt < 16; ++kt) {
        __syncthreads();
#pragma unroll
        for (int ks = 0; ks < 2; ++ks) {
            int kc = ks * 64 + kg * 16;
            bf16x8 af[4];
#pragma unroll
            for (int m = 0; m < 4; ++m) {
                int row = wm * 64 + m * 16 + lr;
                af[m] = *(const bf16x8*)((const char*)lA + row * 128 + (kc ^ ((row & 7) << 4)));
            }
#pragma unroll
            for (int fn = 0; fn < 2; ++fn) {
                int na = wn * 32 + fn * 16 + lr;
                bf16x8 ba = *(const bf16x8*)((const char*)lB + na * 128 + (kc ^ ((na & 7) << 4)));
                bf16x8 bg = *(const bf16x8*)((const char*)lB + (na + 64) * 128 + (kc ^ ((na & 7) << 4)));
#pragma unroll
                for (int m = 0; m < 4; ++m) {
                    aca[m][fn] = MFMA16(af[m], ba, aca[m][fn]);
                    acg[m][fn] = MFMA16(af[m], bg, acg[m][fn]);
                }
            }
        }
        __syncthreads();
        if (kt < 15) {
#pragma unroll
            for (int q = 0; q < 4; ++q) {
                gload16(asrc[q] + (kt + 1) * 64, adst[q]);
                gload16(bsrc[q] + (kt + 1) * 64, bdst[q]);
            }
        }
    }
#pragma unroll
    for (int m = 0; m < 4; ++m)
#pragma unroll
        for (int fn = 0; fn < 2; ++fn) {
            int colh = c0 + wn * 32 + fn * 16 + lr;   // hh col 0..2047
            float ba1 = b1[e * F2 + colh], bg1 = b1[e * F2 + FF + colh];
#pragma unroll
            for (int j = 0; j < 4; ++j) {
                int row = wm * 64 + m * 16 + kg * 4 + j;
                float a = aca[m][fn][j] + ba1;
                float g = acg[m][fn][j] + bg1;
                float sg = a / (1.f + __expf(-a)) * g;
                hh[(size_t)(row0 + row) * FF + colh] = bf16_rne(sg);
            }
        }
}

// ---------------- GEMM2: 128 rows x 64 d-cols, 4 waves, 24KB, 4/CU, eo stores ----------------
__global__ __launch_bounds__(256, 4) void k_gemm2(const unsigned short* __restrict__ hh,
                                                  const unsigned short* __restrict__ W2T,
                                                  const float* __restrict__ b2,
                                                  const int* __restrict__ pair_tok,
                                                  const float* __restrict__ pair_w,
                                                  const int* __restrict__ cnt_pad,
                                                  const int* __restrict__ off_pad,
                                                  float* __restrict__ eo_or_out, int mode) {
    int id = blockIdx.x;
    int lid = (id & 7) * 512 + (id >> 3);
    int d0t = lid & 15, yt = (lid >> 4) & 31, e = lid >> 9;
    if (yt * 128 >= cnt_pad[e]) return;
    int row0 = off_pad[e] + yt * 128;
    int d0 = d0t * 64;
    const unsigned short* WTe = W2T + (size_t)e * 1024 * 2048;

    __shared__ unsigned short lA[128 * 64];
    __shared__ unsigned short lB[64 * 64];

    int t = threadIdx.x, w = t >> 6, l = t & 63;
    int wm = w >> 1, wn = w & 1;

    const unsigned short* asrc[4];
    const unsigned short* bsrc[2];
    unsigned short* adst[4];
    unsigned short* bdst[2];
    int c8 = ((l & 7) ^ (l >> 3)) * 8;
#pragma unroll
    for (int q = 0; q < 4; ++q) {
        int r = w * 32 + q * 8 + (l >> 3);
        asrc[q] = hh + (size_t)(row0 + r) * FF + c8;
        adst[q] = lA + (w * 32 + q * 8) * 64;
    }
#pragma unroll
    for (int q = 0; q < 2; ++q) {
        int r = w * 16 + q * 8 + (l >> 3);
        bsrc[q] = WTe + (size_t)(d0 + r) * 2048 + c8;
        bdst[q] = lB + (w * 16 + q * 8) * 64;
    }

    f32x4 ac[4][2];
#pragma unroll
    for (int m = 0; m < 4; ++m)
#pragma unroll
        for (int fn = 0; fn < 2; ++fn) ac[m][fn] = (f32x4){0,0,0,0};

#pragma unroll
    for (int q = 0; q < 4; ++q) gload16(asrc[q], adst[q]);
#pragma unroll
    for (int q = 0; q < 2; ++q) gload16(bsrc[q], bdst[q]);

    int lr = l & 15, kg = l >> 4;
    for (int kt = 0; kt < 32; ++kt) {
        __syncthreads();
#pragma unroll
        for (int ks = 0; ks < 2; ++ks) {
            int kc = ks * 64 + kg * 16;
            bf16x8 af[4];
#pragma unroll
            for (int m = 0; m < 4; ++m) {
                int row = wm * 64 + m * 16 + lr;
                af[m] = *(const bf16x8*)((const char*)lA + row * 128 + (kc ^ ((row & 7) << 4)));
            }
#pragma unroll
            for (int fn = 0; fn < 2; ++fn) {
                int n = wn * 32 + fn * 16 + lr;
                bf16x8 bb = *(const bf16x8*)((const char*)lB + n * 128 + (kc ^ ((n & 7) << 4)));
#pragma unroll
                for (int m = 0; m < 4; ++m) ac[m][fn] = MFMA16(af[m], bb, ac[m][fn]);
            }
        }
        __syncthreads();
        if (kt < 31) {
#pragma unroll
            for (int q = 0; q < 4; ++q) gload16(asrc[q] + (kt + 1) * 64, adst[q]);
#pragma unroll
            for (int q = 0; q < 2; ++q) gload16(bsrc[q] + (kt + 1) * 64, bdst[q]);
        }
    }

    if (mode == 0) {
#pragma unroll
        for (int m = 0; m < 4; ++m)
#pragma unroll
            for (int fn = 0; fn < 2; ++fn) {
                int col = d0 + wn * 32 + fn * 16 + lr;
#pragma unroll
                for (int j = 0; j < 4; ++j) {
                    int row = wm * 64 + m * 16 + kg * 4 + j;
                    int pr = row0 + row;
                    eo_or_out[(size_t)pr * DM + col] = pair_w[pr] * ac[m][fn][j];
                }
            }
    } else {
#pragma unroll
        for (int m = 0; m < 4; ++m)
#pragma unroll
            for (int fn = 0; fn < 2; ++fn) {
                int col = d0 + wn * 32 + fn * 16 + lr;
                float b2v = b2[e * DM + col];
#pragma unroll
                for (int j = 0; j < 4; ++j) {
                    int row = wm * 64 + m * 16 + kg * 4 + j;
                    int pr = row0 + row;
                    atomicAdd(eo_or_out + (size_t)pair_tok[pr] * DM + col,
                              pair_w[pr] * (ac[m][fn][j] + b2v));
                }
            }
    }
}

// ---------------- combine: out[t] = eo[s0]+eo[s1] + w0*b2[e0] + w1*b2[e1] ----------------
__global__ __launch_bounds__(256) void k_comb(const float* __restrict__ eo,
                                              const int* __restrict__ slot_of,
                                              const int* __restrict__ te,
                                              const float* __restrict__ tw,
                                              const float* __restrict__ b2,
                                              float* __restrict__ out) {
    int t = blockIdx.x;
    int d = threadIdx.x * 4;
    int s0 = slot_of[2*t], s1 = slot_of[2*t+1];
    int e0 = te[2*t], e1 = te[2*t+1];
    float w0 = tw[2*t], w1 = tw[2*t+1];
    float4 a = *(const float4*)(eo + (size_t)s0 * DM + d);
    float4 b = *(const float4*)(eo + (size_t)s1 * DM + d);
    float4 p = *(const float4*)(b2 + (size_t)e0 * DM + d);
    float4 q = *(const float4*)(b2 + (size_t)e1 * DM + d);
    float4 r;
    r.x = a.x + b.x + w0 * p.x + w1 * q.x;
    r.y = a.y + b.y + w0 * p.y + w1 * q.y;
    r.z = a.z + b.z + w0 * p.z + w1 * q.z;
    r.w = a.w + b.w + w0 * p.w + w1 * q.w;
    *(float4*)(out + (size_t)t * DM + d) = r;
}

// ---------------- host ----------------
extern "C" void kernel_launch(void* const* d_in, const int* in_sizes, int n_in,
                              void* d_out, int out_size, void* d_ws, size_t ws_size,
                              hipStream_t stream) {
    const float* x  = (const float*)d_in[0];
    const float* Wg = (const float*)d_in[1];
    const float* W1 = (const float*)d_in[2];
    const float* b1 = (const float*)d_in[3];
    const float* W2 = (const float*)d_in[4];
    const float* b2 = (const float*)d_in[5];
    float* out = (float*)d_out;

    char* ws = (char*)d_ws;
    unsigned short* xbf = (unsigned short*)ws;                        // 8.39 MB
    unsigned short* hh  = (unsigned short*)(ws + 8388608);            // 41.94 MB
    unsigned short* W1T = (unsigned short*)(ws + 50331648);           // 67.11 MB (full, both halves)
    unsigned short* W2Tm0 = (unsigned short*)(ws + 117440512);        // 33.55 MB
    float* eo           = (float*)(ws + 150994944);                   // 41.94 MB
    const size_t MODE0_END = 150994944ull + 41943040ull;              // 192.9 MB
    int mode = (ws_size >= MODE0_END + 262144) ? 0 : 1;
    size_t mb = (mode == 0) ? MODE0_END : 117440512ull;
    unsigned short* W2T = (mode == 0) ? W2Tm0 : (unsigned short*)(ws + 50331648);
    int*   pair_tok = (int*)(ws + mb);
    float* pair_w   = (float*)(ws + mb + 40960);
    int*   slot_of  = (int*)(ws + mb + 81920);
    int*   te       = (int*)(ws + mb + 114688);
    float* tw       = (float*)(ws + mb + 147456);
    int*   cnt_pad  = (int*)(ws + mb + 180224);
    int*   off_pad  = (int*)(ws + mb + 180352);

    if (mode == 1)
        hipMemsetAsync(d_out, 0, (size_t)out_size * sizeof(float), stream);

    k_gate<<<NTOK / 4, 256, 0, stream>>>(x, Wg, xbf, te, tw);
    k_route<<<1, 256, 0, stream>>>(te, tw, pair_tok, pair_w, slot_of, cnt_pad, off_pad);

    k_cvt1<<<dim3(16, 64, 8), 256, 0, stream>>>(W1, W1T);
    k_gemm1<<<8192, 256, 0, stream>>>(xbf, W1T, b1, pair_tok, cnt_pad, off_pad, hh);
    k_cvt2<<<dim3(32, 16, 8), 256, 0, stream>>>(W2, W2T);
    k_gemm2<<<4096, 256, 0, stream>>>(hh, W2T, b2, pair_tok, pair_w, cnt_pad, off_pad,
                                      (mode == 0) ? eo : out, mode);
    if (mode == 0)
        k_comb<<<NTOK, 256, 0, stream>>>(eo, slot_of, te, tw, b2, out);
}

// Round 17
// 222.213 us; speedup vs baseline: 1.5102x; 1.0198x over previous
//
#include <hip/hip_runtime.h>
#include <hip/hip_bf16.h>
#include <stdint.h>

#define NTOK 4096
#define DM 1024
#define FF 2048
#define F2 4096
#define NEXP 8
#define PAIR_CAP 10240

typedef __bf16 bf16x8 __attribute__((ext_vector_type(8)));
typedef float f32x4 __attribute__((ext_vector_type(4)));

__device__ __forceinline__ unsigned short bf16_rne(float f) {
    union { float f; unsigned int u; } v; v.f = f;
    unsigned int u = v.u;
    return (unsigned short)((u + 0x7FFFu + ((u >> 16) & 1u)) >> 16);
}

__device__ __forceinline__ f32x4 MFMA16(bf16x8 a, bf16x8 b, f32x4 c) {
    return __builtin_amdgcn_mfma_f32_16x16x32_bf16(a, b, c, 0, 0, 0);
}

__device__ __forceinline__ void gload16(const void* g, void* l) {
    __builtin_amdgcn_global_load_lds(
        (const __attribute__((address_space(1))) uint32_t*)g,
        (__attribute__((address_space(3))) uint32_t*)l, 16, 0, 0);
}

// ---------------- prep: cvt1 | cvt2 | gate fused (independent segments, 1 launch) ----------------
__global__ __launch_bounds__(256) void k_prep(const float* __restrict__ W1,
                                              unsigned short* __restrict__ W1T,
                                              const float* __restrict__ W2,
                                              unsigned short* __restrict__ W2T,
                                              const float* __restrict__ x,
                                              const float* __restrict__ Wg,
                                              unsigned short* __restrict__ xbf,
                                              int* __restrict__ te, float* __restrict__ tw) {
    __shared__ float lt[64][65];
    int b = blockIdx.x;
    int t = threadIdx.x;
    if (b < 8192) {
        // ---- cvt1: W1 fp32 [e][1024k][4096f] -> W1T bf16 [e][4096n][1024k] ----
        int kt = b & 15, nt = (b >> 4) & 63, e = b >> 10;
        int col0 = (nt < 32) ? (nt * 64) : (FF + (nt - 32) * 64);
        const float* src = W1 + (size_t)e * DM * F2 + (size_t)(kt * 64) * F2 + col0;
#pragma unroll
        for (int i = 0; i < 4; ++i) {
            int flat = i * 256 + t;
            int k = flat >> 4, c4 = (flat & 15) * 4;
            float4 v = *(const float4*)(src + (size_t)k * F2 + c4);
            lt[k][c4] = v.x; lt[k][c4+1] = v.y; lt[k][c4+2] = v.z; lt[k][c4+3] = v.w;
        }
        __syncthreads();
        unsigned short* dst = W1T + ((size_t)e * 4096 + nt * 64) * 1024 + kt * 64;
#pragma unroll
        for (int i = 0; i < 4; ++i) {
            int flat = i * 256 + t;
            int n = flat >> 4, kc = (flat & 15) * 4;
            unsigned int lo = (unsigned int)bf16_rne(lt[kc][n])   | ((unsigned int)bf16_rne(lt[kc+1][n]) << 16);
            unsigned int hi = (unsigned int)bf16_rne(lt[kc+2][n]) | ((unsigned int)bf16_rne(lt[kc+3][n]) << 16);
            *(uint2*)(dst + (size_t)n * 1024 + kc) = make_uint2(lo, hi);
        }
    } else if (b < 12288) {
        // ---- cvt2: W2 fp32 [e][2048k][1024d] -> W2T bf16 [e][1024n][2048k] ----
        int c = b - 8192;
        int kt = c & 31, nt = (c >> 5) & 15, e = c >> 9;
        const float* src = W2 + (size_t)e * FF * DM + (size_t)(kt * 64) * DM + nt * 64;
#pragma unroll
        for (int i = 0; i < 4; ++i) {
            int flat = i * 256 + t;
            int k = flat >> 4, c4 = (flat & 15) * 4;
            float4 v = *(const float4*)(src + (size_t)k * DM + c4);
            lt[k][c4] = v.x; lt[k][c4+1] = v.y; lt[k][c4+2] = v.z; lt[k][c4+3] = v.w;
        }
        __syncthreads();
        unsigned short* dst = W2T + ((size_t)e * 1024 + nt * 64) * 2048 + kt * 64;
#pragma unroll
        for (int i = 0; i < 4; ++i) {
            int flat = i * 256 + t;
            int n = flat >> 4, kc = (flat & 15) * 4;
            unsigned int lo = (unsigned int)bf16_rne(lt[kc][n])   | ((unsigned int)bf16_rne(lt[kc+1][n]) << 16);
            unsigned int hi = (unsigned int)bf16_rne(lt[kc+2][n]) | ((unsigned int)bf16_rne(lt[kc+3][n]) << 16);
            *(uint2*)(dst + (size_t)n * 2048 + kc) = make_uint2(lo, hi);
        }
    } else {
        // ---- gate: scores (fp32), top-2 softmax, x -> bf16; NO atomics ----
        int tok = (b - 12288) * 4 + (t >> 6);
        int l = t & 63;
        const float* xr = x + (size_t)tok * DM + l * 16;
        float xv[16];
#pragma unroll
        for (int i = 0; i < 4; ++i) {
            float4 v = ((const float4*)xr)[i];
            xv[4*i+0] = v.x; xv[4*i+1] = v.y; xv[4*i+2] = v.z; xv[4*i+3] = v.w;
        }
        unsigned int pk[8];
#pragma unroll
        for (int i = 0; i < 8; ++i)
            pk[i] = (unsigned int)bf16_rne(xv[2*i]) | ((unsigned int)bf16_rne(xv[2*i+1]) << 16);
        uint4* dst = (uint4*)(xbf + (size_t)tok * DM + l * 16);
        dst[0] = make_uint4(pk[0], pk[1], pk[2], pk[3]);
        dst[1] = make_uint4(pk[4], pk[5], pk[6], pk[7]);

        float s[NEXP];
#pragma unroll
        for (int e = 0; e < NEXP; ++e) {
            const float* wr = Wg + e * DM + l * 16;
            float acc = 0.f;
#pragma unroll
            for (int i = 0; i < 4; ++i) {
                float4 v = ((const float4*)wr)[i];
                acc += v.x * xv[4*i] + v.y * xv[4*i+1] + v.z * xv[4*i+2] + v.w * xv[4*i+3];
            }
            s[e] = acc;
        }
#pragma unroll
        for (int off = 32; off > 0; off >>= 1) {
#pragma unroll
            for (int e = 0; e < NEXP; ++e) s[e] += __shfl_xor(s[e], off, 64);
        }
        if (l == 0) {
            int e0 = 0; float v0 = s[0];
            for (int e = 1; e < NEXP; ++e) if (s[e] > v0) { v0 = s[e]; e0 = e; }
            int e1 = -1; float v1 = -1e30f;
            for (int e = 0; e < NEXP; ++e) if (e != e0 && s[e] > v1) { v1 = s[e]; e1 = e; }
            float w0 = 1.f / (1.f + __expf(v1 - v0));
            float w1 = 1.f - w0;
            te[2*tok] = e0; te[2*tok+1] = e1;
            tw[2*tok] = w0; tw[2*tok+1] = w1;
        }
    }
}

// ---------------- route: deterministic prefix-sum placement, NO atomics, 1 block ----------------
__global__ __launch_bounds__(256) void k_route(const int* __restrict__ te,
                                               const float* __restrict__ tw,
                                               int* __restrict__ pair_tok, float* __restrict__ pair_w,
                                               int* __restrict__ slot_of,
                                               int* __restrict__ cnt_pad, int* __restrict__ off_pad) {
    __shared__ int lc[256][NEXP];
    __shared__ int opad[NEXP];
    int t = threadIdx.x;
    for (int i = t; i < PAIR_CAP; i += 256) { pair_tok[i] = 0; pair_w[i] = 0.f; }
    int ev[32];
    int c[NEXP];
#pragma unroll
    for (int e = 0; e < NEXP; ++e) c[e] = 0;
#pragma unroll
    for (int j = 0; j < 32; ++j) {
        ev[j] = te[t * 32 + j];
#pragma unroll
        for (int e = 0; e < NEXP; ++e) c[e] += (ev[j] == e) ? 1 : 0;
    }
#pragma unroll
    for (int e = 0; e < NEXP; ++e) lc[t][e] = c[e];
    __syncthreads();
    if (t < NEXP) {
        int run = 0;
        for (int i = 0; i < 256; ++i) { int v = lc[i][t]; lc[i][t] = run; run += v; }
        opad[t] = run;
    }
    __syncthreads();
    if (t == 0) {
        int o = 0;
        for (int e = 0; e < NEXP; ++e) {
            int tot = opad[e];
            int cp = ((tot + 127) >> 7) << 7;
            cnt_pad[e] = cp; off_pad[e] = o; opad[e] = o; o += cp;
        }
    }
    __syncthreads();
    int cur[NEXP];
#pragma unroll
    for (int e = 0; e < NEXP; ++e) cur[e] = opad[e] + lc[t][e];
#pragma unroll
    for (int j = 0; j < 32; ++j) {
        int p = t * 32 + j;
        int slot = 0;
#pragma unroll
        for (int e = 0; e < NEXP; ++e) {
            bool m = (ev[j] == e);
            if (m) slot = cur[e];
            cur[e] += m ? 1 : 0;
        }
        pair_tok[slot] = p >> 1;
        pair_w[slot] = tw[p];
        slot_of[p] = slot;
    }
}

// ---------------- GEMM1: 128 rows x 64 hh-cols, 4 waves, 32KB, 4/CU (R13/R16 proven) ----------------
// grid 8192 XCD-chunked; lid = c0t(5b) | yt(5b) | e(3b); active ~2048
__global__ __launch_bounds__(256, 4) void k_gemm1(const unsigned short* __restrict__ xbf,
                                                  const unsigned short* __restrict__ W1T,
                                                  const float* __restrict__ b1,
                                                  const int* __restrict__ pair_tok,
                                                  const int* __restrict__ cnt_pad,
                                                  const int* __restrict__ off_pad,
                                                  unsigned short* __restrict__ hh) {
    int id = blockIdx.x;
    int lid = (id & 7) * 1024 + (id >> 3);
    int c0t = lid & 31, yt = (lid >> 5) & 31, e = lid >> 10;
    if (yt * 128 >= cnt_pad[e]) return;
    int row0 = off_pad[e] + yt * 128;
    int c0 = c0t * 64;
    const unsigned short* WTe = W1T + (size_t)e * 4096 * 1024;

    __shared__ unsigned short lA[128 * 64];
    __shared__ unsigned short lB[128 * 64];

    int t = threadIdx.x, w = t >> 6, l = t & 63;
    int wm = w >> 1, wn = w & 1;

    const unsigned short* asrc[4];
    const unsigned short* bsrc[4];
    unsigned short* adst[4];
    unsigned short* bdst[4];
    int c8 = ((l & 7) ^ (l >> 3)) * 8;
#pragma unroll
    for (int q = 0; q < 4; ++q) {
        int r = w * 32 + q * 8 + (l >> 3);
        int tok = pair_tok[row0 + r];
        asrc[q] = xbf + (size_t)tok * DM + c8;
        adst[q] = lA + (w * 32 + q * 8) * 64;
        int bn = (r < 64) ? (c0 + r) : (2048 + c0 + (r - 64));   // a rows then g rows
        bsrc[q] = WTe + (size_t)bn * 1024 + c8;
        bdst[q] = lB + (w * 32 + q * 8) * 64;
    }

    f32x4 aca[4][2], acg[4][2];
#pragma unroll
    for (int m = 0; m < 4; ++m)
#pragma unroll
        for (int fn = 0; fn < 2; ++fn) { aca[m][fn] = (f32x4){0,0,0,0}; acg[m][fn] = (f32x4){0,0,0,0}; }

#pragma unroll
    for (int q = 0; q < 4; ++q) { gload16(asrc[q], adst[q]); gload16(bsrc[q], bdst[q]); }

    int lr = l & 15, kg = l >> 4;
    for (int kt = 0; kt < 16; ++kt) {
        __syncthreads();
#pragma unroll
        for (int ks = 0; ks < 2; ++ks) {
            int kc = ks * 64 + kg * 16;
            bf16x8 af[4];
#pragma unroll
            for (int m = 0; m < 4; ++m) {
                int row = wm * 64 + m * 16 + lr;
                af[m] = *(const bf16x8*)((const char*)lA + row * 128 + (kc ^ ((row & 7) << 4)));
            }
#pragma unroll
            for (int fn = 0; fn < 2; ++fn) {
                int na = wn * 32 + fn * 16 + lr;
                bf16x8 ba = *(const bf16x8*)((const char*)lB + na * 128 + (kc ^ ((na & 7) << 4)));
                bf16x8 bg = *(const bf16x8*)((const char*)lB + (na + 64) * 128 + (kc ^ ((na & 7) << 4)));
#pragma unroll
                for (int m = 0; m < 4; ++m) {
                    aca[m][fn] = MFMA16(af[m], ba, aca[m][fn]);
                    acg[m][fn] = MFMA16(af[m], bg, acg[m][fn]);
                }
            }
        }
        __syncthreads();
        if (kt < 15) {
#pragma unroll
            for (int q = 0; q < 4; ++q) {
                gload16(asrc[q] + (kt + 1) * 64, adst[q]);
                gload16(bsrc[q] + (kt + 1) * 64, bdst[q]);
            }
        }
    }
#pragma unroll
    for (int m = 0; m < 4; ++m)
#pragma unroll
        for (int fn = 0; fn < 2; ++fn) {
            int colh = c0 + wn * 32 + fn * 16 + lr;   // hh col 0..2047
            float ba1 = b1[e * F2 + colh], bg1 = b1[e * F2 + FF + colh];
#pragma unroll
            for (int j = 0; j < 4; ++j) {
                int row = wm * 64 + m * 16 + kg * 4 + j;
                float a = aca[m][fn][j] + ba1;
                float g = acg[m][fn][j] + bg1;
                float sg = a / (1.f + __expf(-a)) * g;
                hh[(size_t)(row0 + row) * FF + colh] = bf16_rne(sg);
            }
        }
}

// ---------------- GEMM2: 128 rows x 64 d-cols, 4 waves, 24KB, 4/CU, eo stores ----------------
__global__ __launch_bounds__(256, 4) void k_gemm2(const unsigned short* __restrict__ hh,
                                                  const unsigned short* __restrict__ W2T,
                                                  const float* __restrict__ b2,
                                                  const int* __restrict__ pair_tok,
                                                  const float* __restrict__ pair_w,
                                                  const int* __restrict__ cnt_pad,
                                                  const int* __restrict__ off_pad,
                                                  float* __restrict__ eo_or_out, int mode) {
    int id = blockIdx.x;
    int lid = (id & 7) * 512 + (id >> 3);
    int d0t = lid & 15, yt = (lid >> 4) & 31, e = lid >> 9;
    if (yt * 128 >= cnt_pad[e]) return;
    int row0 = off_pad[e] + yt * 128;
    int d0 = d0t * 64;
    const unsigned short* WTe = W2T + (size_t)e * 1024 * 2048;

    __shared__ unsigned short lA[128 * 64];
    __shared__ unsigned short lB[64 * 64];

    int t = threadIdx.x, w = t >> 6, l = t & 63;
    int wm = w >> 1, wn = w & 1;

    const unsigned short* asrc[4];
    const unsigned short* bsrc[2];
    unsigned short* adst[4];
    unsigned short* bdst[2];
    int c8 = ((l & 7) ^ (l >> 3)) * 8;
#pragma unroll
    for (int q = 0; q < 4; ++q) {
        int r = w * 32 + q * 8 + (l >> 3);
        asrc[q] = hh + (size_t)(row0 + r) * FF + c8;
        adst[q] = lA + (w * 32 + q * 8) * 64;
    }
#pragma unroll
    for (int q = 0; q < 2; ++q) {
        int r = w * 16 + q * 8 + (l >> 3);
        bsrc[q] = WTe + (size_t)(d0 + r) * 2048 + c8;
        bdst[q] = lB + (w * 16 + q * 8) * 64;
    }

    f32x4 ac[4][2];
#pragma unroll
    for (int m = 0; m < 4; ++m)
#pragma unroll
        for (int fn = 0; fn < 2; ++fn) ac[m][fn] = (f32x4){0,0,0,0};

#pragma unroll
    for (int q = 0; q < 4; ++q) gload16(asrc[q], adst[q]);
#pragma unroll
    for (int q = 0; q < 2; ++q) gload16(bsrc[q], bdst[q]);

    int lr = l & 15, kg = l >> 4;
    for (int kt = 0; kt < 32; ++kt) {
        __syncthreads();
#pragma unroll
        for (int ks = 0; ks < 2; ++ks) {
            int kc = ks * 64 + kg * 16;
            bf16x8 af[4];
#pragma unroll
            for (int m = 0; m < 4; ++m) {
                int row = wm * 64 + m * 16 + lr;
                af[m] = *(const bf16x8*)((const char*)lA + row * 128 + (kc ^ ((row & 7) << 4)));
            }
#pragma unroll
            for (int fn = 0; fn < 2; ++fn) {
                int n = wn * 32 + fn * 16 + lr;
                bf16x8 bb = *(const bf16x8*)((const char*)lB + n * 128 + (kc ^ ((n & 7) << 4)));
#pragma unroll
                for (int m = 0; m < 4; ++m) ac[m][fn] = MFMA16(af[m], bb, ac[m][fn]);
            }
        }
        __syncthreads();
        if (kt < 31) {
#pragma unroll
            for (int q = 0; q < 4; ++q) gload16(asrc[q] + (kt + 1) * 64, adst[q]);
#pragma unroll
            for (int q = 0; q < 2; ++q) gload16(bsrc[q] + (kt + 1) * 64, bdst[q]);
        }
    }

    if (mode == 0) {
#pragma unroll
        for (int m = 0; m < 4; ++m)
#pragma unroll
            for (int fn = 0; fn < 2; ++fn) {
                int col = d0 + wn * 32 + fn * 16 + lr;
#pragma unroll
                for (int j = 0; j < 4; ++j) {
                    int row = wm * 64 + m * 16 + kg * 4 + j;
                    int pr = row0 + row;
                    eo_or_out[(size_t)pr * DM + col] = pair_w[pr] * ac[m][fn][j];
                }
            }
    } else {
#pragma unroll
        for (int m = 0; m < 4; ++m)
#pragma unroll
            for (int fn = 0; fn < 2; ++fn) {
                int col = d0 + wn * 32 + fn * 16 + lr;
                float b2v = b2[e * DM + col];
#pragma unroll
                for (int j = 0; j < 4; ++j) {
                    int row = wm * 64 + m * 16 + kg * 4 + j;
                    int pr = row0 + row;
                    atomicAdd(eo_or_out + (size_t)pair_tok[pr] * DM + col,
                              pair_w[pr] * (ac[m][fn][j] + b2v));
                }
            }
    }
}

// ---------------- combine: out[t] = eo[s0]+eo[s1] + w0*b2[e0] + w1*b2[e1] ----------------
__global__ __launch_bounds__(256) void k_comb(const float* __restrict__ eo,
                                              const int* __restrict__ slot_of,
                                              const int* __restrict__ te,
                                              const float* __restrict__ tw,
                                              const float* __restrict__ b2,
                                              float* __restrict__ out) {
    int t = blockIdx.x;
    int d = threadIdx.x * 4;
    int s0 = slot_of[2*t], s1 = slot_of[2*t+1];
    int e0 = te[2*t], e1 = te[2*t+1];
    float w0 = tw[2*t], w1 = tw[2*t+1];
    float4 a = *(const float4*)(eo + (size_t)s0 * DM + d);
    float4 b = *(const float4*)(eo + (size_t)s1 * DM + d);
    float4 p = *(const float4*)(b2 + (size_t)e0 * DM + d);
    float4 q = *(const float4*)(b2 + (size_t)e1 * DM + d);
    float4 r;
    r.x = a.x + b.x + w0 * p.x + w1 * q.x;
    r.y = a.y + b.y + w0 * p.y + w1 * q.y;
    r.z = a.z + b.z + w0 * p.z + w1 * q.z;
    r.w = a.w + b.w + w0 * p.w + w1 * q.w;
    *(float4*)(out + (size_t)t * DM + d) = r;
}

// ---------------- host ----------------
extern "C" void kernel_launch(void* const* d_in, const int* in_sizes, int n_in,
                              void* d_out, int out_size, void* d_ws, size_t ws_size,
                              hipStream_t stream) {
    const float* x  = (const float*)d_in[0];
    const float* Wg = (const float*)d_in[1];
    const float* W1 = (const float*)d_in[2];
    const float* b1 = (const float*)d_in[3];
    const float* W2 = (const float*)d_in[4];
    const float* b2 = (const float*)d_in[5];
    float* out = (float*)d_out;

    char* ws = (char*)d_ws;
    unsigned short* xbf = (unsigned short*)ws;                        // 8.39 MB
    unsigned short* hh  = (unsigned short*)(ws + 8388608);            // 41.94 MB
    unsigned short* W1T = (unsigned short*)(ws + 50331648);           // 67.11 MB (full, both halves)
    unsigned short* W2Tm0 = (unsigned short*)(ws + 117440512);        // 33.55 MB
    float* eo           = (float*)(ws + 150994944);                   // 41.94 MB
    const size_t MODE0_END = 150994944ull + 41943040ull;              // 192.9 MB
    int mode = (ws_size >= MODE0_END + 262144) ? 0 : 1;
    size_t mb = (mode == 0) ? MODE0_END : 117440512ull;
    unsigned short* W2T = (mode == 0) ? W2Tm0 : (unsigned short*)(ws + 50331648);
    int*   pair_tok = (int*)(ws + mb);
    float* pair_w   = (float*)(ws + mb + 40960);
    int*   slot_of  = (int*)(ws + mb + 81920);
    int*   te       = (int*)(ws + mb + 114688);
    float* tw       = (float*)(ws + mb + 147456);
    int*   cnt_pad  = (int*)(ws + mb + 180224);
    int*   off_pad  = (int*)(ws + mb + 180352);

    if (mode == 1)
        hipMemsetAsync(d_out, 0, (size_t)out_size * sizeof(float), stream);

    // fused prep: cvt1 (8192 blocks) | cvt2 (4096) | gate (1024)
    k_prep<<<13312, 256, 0, stream>>>(W1, W1T, W2, W2T, x, Wg, xbf, te, tw);
    k_route<<<1, 256, 0, stream>>>(te, tw, pair_tok, pair_w, slot_of, cnt_pad, off_pad);
    k_gemm1<<<8192, 256, 0, stream>>>(xbf, W1T, b1, pair_tok, cnt_pad, off_pad, hh);
    k_gemm2<<<4096, 256, 0, stream>>>(hh, W2T, b2, pair_tok, pair_w, cnt_pad, off_pad,
                                      (mode == 0) ? eo : out, mode);
    if (mode == 0)
        k_comb<<<NTOK, 256, 0, stream>>>(eo, slot_of, te, tw, b2, out);
}